// Round 16
// baseline (3400.655 us; speedup 1.0000x reference)
//
#include <hip/hip_runtime.h>

#define T_ 12
#define L_ 1024
#define H_ 64
#define HOR_ 12
#define BH_ 2048

typedef unsigned short u16;
typedef __attribute__((ext_vector_type(8))) __bf16 bf16x8;
typedef __attribute__((ext_vector_type(8))) u16 u16x8;
typedef __attribute__((ext_vector_type(4))) float f32x4;

__device__ __forceinline__ u16 f2b(float f) {
  union { float f; unsigned u; } v; v.f = f;
  unsigned r = v.u + 0x7FFFu + ((v.u >> 16) & 1u);
  return (u16)(r >> 16);
}
__device__ __forceinline__ float b2f(u16 b) {
  union { unsigned u; float f; } v; v.u = ((unsigned)b) << 16;
  return v.f;
}
__device__ __forceinline__ void gld16(const void* g, void* l) {
  __builtin_amdgcn_global_load_lds((const __attribute__((address_space(1))) void*)g,
                                   (__attribute__((address_space(3))) void*)l, 16, 0, 0);
}

// manual grid barrier: 256 blocks, all provably co-resident (4 blocks/CU capacity)
__device__ __forceinline__ void gbar(unsigned* cnt, unsigned target) {
  __syncthreads();
  if (threadIdx.x == 0) {
    __threadfence();   // release my global writes
    __hip_atomic_fetch_add(cnt, 1u, __ATOMIC_RELEASE, __HIP_MEMORY_SCOPE_AGENT);
    while (__hip_atomic_load(cnt, __ATOMIC_ACQUIRE, __HIP_MEMORY_SCOPE_AGENT) < target)
      __builtin_amdgcn_s_sleep(2);
  }
  __syncthreads();
  __threadfence();     // acquire: don't use stale cached lines
}

// ---- fused prep (round-12 version + barrier-counter zeroing) ----
__global__ __launch_bounds__(256) void k_prep(
    const float* __restrict__ Wh, const float* __restrict__ Wi, const float* __restrict__ x,
    u16* __restrict__ WhT, u16* __restrict__ Wib, u16* __restrict__ xb,
    const float* __restrict__ Wr, const float* __restrict__ Wz, const float* __restrict__ Wn,
    u16* __restrict__ WTr, u16* __restrict__ WTz, u16* __restrict__ WTn,
    const float* __restrict__ brh, const float* __restrict__ bri,
    const float* __restrict__ bzh, const float* __restrict__ bzi,
    const float* __restrict__ bnh, const float* __restrict__ bni,
    float* __restrict__ BRZ, float* __restrict__ BZZ,
    float* __restrict__ BNH, float* __restrict__ BNI, unsigned* __restrict__ BAR) {
  __shared__ u16 lds[64][66];
  const int bid = blockIdx.x, tid = threadIdx.x;
  if (bid == 0 && tid == 0) *BAR = 0u;
  if (bid < 1792) {                       // ---- cvt: Wi | x ----
    const float* in; u16* out; int i;
    if (bid < 1024) { in = Wi; out = Wib; i = bid * 256 + tid; }
    else            { in = x;  out = xb;  i = (bid - 1024) * 256 + tid; }
    float4 v = ((const float4*)in)[i];
    ushort4 o;
    o.x = f2b(v.x); o.y = f2b(v.y); o.z = f2b(v.z); o.w = f2b(v.w);
    ((ushort4*)out)[i] = o;
  } else if (bid < 2048) {                // ---- WhT: tile Wh into fragment order ----
    const int q = bid - 1792;
    const int mt = q >> 4, kt = q & 15;
    u16* dst = WhT + (size_t)(mt * 16 + kt) * 4096;
#pragma unroll
    for (int j = 0; j < 2; ++j) {
      int ci = j * 256 + tid;
      int ln = ci & 63, kt2 = (ci >> 6) & 1, uu = (ci >> 7) & 1, gh = (ci >> 8) & 1;
      int rw = gh * 32 + uu * 16 + (ln & 15);
      int cw0 = kt2 * 32 + (ln >> 4) * 8;
      const float* src = Wh + (size_t)(mt * 64 + rw) * 1024 + kt * 64 + cw0;
      float4 v0 = *(const float4*)src, v1 = *(const float4*)(src + 4);
      u16x8 o;
      o[0] = f2b(v0.x); o[1] = f2b(v0.y); o[2] = f2b(v0.z); o[3] = f2b(v0.w);
      o[4] = f2b(v1.x); o[5] = f2b(v1.y); o[6] = f2b(v1.z); o[7] = f2b(v1.w);
      *(u16x8*)(dst + ci * 8) = o;
    }
  } else if (bid < 5120) {                // ---- transpose WT[l][k][h] = W[l][h][k] ----
    const int q = bid - 2048;
    const int sel = q >> 10, l = q & 1023;
    const float* w = (sel == 0 ? Wr : sel == 1 ? Wz : Wn) + (size_t)l * 4096;
    u16* t = (sel == 0 ? WTr : sel == 1 ? WTz : WTn) + (size_t)l * 4096;
#pragma unroll
    for (int j = 0; j < 16; ++j) {
      int idx = j * 256 + tid;
      lds[idx & 63][idx >> 6] = f2b(w[idx]);
    }
    __syncthreads();
#pragma unroll
    for (int j = 0; j < 2; ++j) {
      int w8 = j * 256 + tid;
      int k = w8 >> 3, h0 = (w8 & 7) * 8;
      u16x8 v;
#pragma unroll
      for (int e = 0; e < 8; ++e) v[e] = lds[k][h0 + e];
      *(u16x8*)(t + k * 64 + h0) = v;
    }
  } else {                                // ---- bias transpose+combine ----
    const int idx = (bid - 5120) * 256 + tid;
    const int l = idx >> 6, k = idx & 63;
    const int i = k * 1024 + l, o = l * 64 + k;
    BRZ[o] = brh[i] + bri[i];
    BZZ[o] = bzh[i] + bzi[i];
    BNH[o] = bnh[i];
    BNI[o] = bni[i];
  }
}

// -------- legacy 64x128 NT GEMM (one-time ENCIN) --------
__global__ __launch_bounds__(256) void k_gemm_nt(const u16* __restrict__ A,
                                                 const u16* __restrict__ Bm,
                                                 float* __restrict__ C, int N, int K) {
  __shared__ __align__(16) u16 lA[64 * 64];
  __shared__ __align__(16) u16 lB[128 * 64];
  const int tid = threadIdx.x;
  const int lane = tid & 63, wv = tid >> 6;
  const int m0 = blockIdx.y * 64, n0 = blockIdx.x * 128;
  const int g2 = wv >> 1, gb = wv & 1;
  const int wm = g2 * 32, wn = gb * 64;
  const int r16 = lane & 15, q4 = lane >> 4;
  f32x4 acc[2][4] = {};
  for (int k0 = 0; k0 < K; k0 += 64) {
    __syncthreads();
#pragma unroll
    for (int j = 0; j < 2; ++j) {
      int ci = j * 256 + tid;
      int ln = ci & 63, kt = (ci >> 6) & 1, u = (ci >> 7) & 1, g = ci >> 8;
      int row = g * 32 + u * 16 + (ln & 15), c = kt * 4 + ((ln >> 4) & 3);
      gld16(A + (size_t)(m0 + row) * K + k0 + c * 8, lA + ci * 8);
    }
#pragma unroll
    for (int j = 0; j < 4; ++j) {
      int ci = j * 256 + tid;
      int ln = ci & 63, kt = (ci >> 6) & 1, u = (ci >> 7) & 3, g = ci >> 9;
      int row = g * 64 + u * 16 + (ln & 15), c = kt * 4 + ((ln >> 4) & 3);
      gld16(Bm + (size_t)(n0 + row) * K + k0 + c * 8, lB + ci * 8);
    }
    __syncthreads();
#pragma unroll
    for (int kt = 0; kt < 2; ++kt) {
      bf16x8 af[2], bfv[4];
#pragma unroll
      for (int u = 0; u < 2; ++u)
        af[u] = *(const bf16x8*)&lA[((g2 * 2 + u) * 2 + kt) * 512 + lane * 8];
#pragma unroll
      for (int u = 0; u < 4; ++u)
        bfv[u] = *(const bf16x8*)&lB[((gb * 4 + u) * 2 + kt) * 512 + lane * 8];
#pragma unroll
      for (int i = 0; i < 2; ++i)
#pragma unroll
        for (int j = 0; j < 4; ++j)
          acc[i][j] = __builtin_amdgcn_mfma_f32_16x16x32_bf16(af[i], bfv[j], acc[i][j], 0, 0, 0);
    }
  }
#pragma unroll
  for (int i = 0; i < 2; ++i)
#pragma unroll
    for (int j = 0; j < 4; ++j)
#pragma unroll
      for (int e = 0; e < 4; ++e) {
        size_t row = m0 + wm + i * 16 + q4 * 4 + e;
        size_t col = n0 + wn + j * 16 + r16;
        C[row * N + col] = acc[i][j][e];
      }
}

// -------- persistent recurrence: 23 steps, manual grid barrier, 256 blocks --------
struct KP {
  const u16* WhT; u16* HbT; u16* Aalt;
  const u16 *WTr, *WTz, *WTn;
  const float *BRZ, *BZZ, *BNH, *BNI;
  const float *Wir, *Wiz, *Win;
  const float* ENCIN;
  const u16* Wib;
  const float *fcw, *fcb;
  float* outp;
  u16 *OFC0, *OFC1;
  unsigned* BAR;
};

__global__ __launch_bounds__(512, 2) void k_fused(KP p) {
  __shared__ __align__(16) char smraw[32768];

  const int tid = threadIdx.x;
  const int lane = tid & 63;
  const int bid = blockIdx.x;
  const int r16 = lane & 15, q4 = lane >> 4;
  // GEMM identity: half h handles tile T = bid*2+h
  const int h = tid >> 8, tid_h = tid & 255, wvh = tid_h >> 6;
  const int gA = wvh >> 1, gB = wvh & 1;
  const int T0 = bid * 2 + h, NT = T0 & 31, MT = T0 >> 5;
  // per-half LDS pointers (plain arithmetic — no addrspacecast array init)
  u16* lA = (u16*)(smraw + h * 8192);
  u16* lB = (u16*)(smraw + 16384 + h * 8192);
  // gates-phase LDS views
  u16* lout = (u16*)smraw;                 // 8KB
  u16* lWi  = (u16*)(smraw + 16384);       // 4KB
  float* din = (float*)(smraw + 20480);    // 512B  [(li*2+f)*32+b]
  // gates identity: 4 links/block, chunked XCD map
  const int wv = tid >> 6;
  const int li = (wv >> 2) & 1, mh = (wv >> 1) & 1, nh = wv & 1;
  const int wg4 = (bid & 7) * 32 + (bid >> 3);
  unsigned phase = 0;

  for (int step = 0; step < 23; ++step) {
    // ================= GEMM: Aalt = WhT x HbT^T, two 64x64 tiles/block =================
    if (step > 0) {
      const u16* srcA = p.WhT + (size_t)MT * 16 * 4096;
      const u16* srcB = p.HbT + (size_t)NT * 16 * 4096;
      f32x4 acc[2][2] = {};
      for (int s = 0; s < 16; ++s) {
        __syncthreads();
#pragma unroll
        for (int j = 0; j < 2; ++j) {
          int ci = j * 256 + tid_h;
          gld16(srcA + (size_t)s * 4096 + ci * 8, lA + ci * 8);
          gld16(srcB + (size_t)s * 4096 + ci * 8, lB + ci * 8);
        }
        __syncthreads();
#pragma unroll
        for (int kt = 0; kt < 2; ++kt) {
          bf16x8 af[2], bfv[2];
#pragma unroll
          for (int u = 0; u < 2; ++u) {
            af[u]  = *(const bf16x8*)&lA[((gA * 2 + u) * 2 + kt) * 512 + lane * 8];
            bfv[u] = *(const bf16x8*)&lB[((gB * 2 + u) * 2 + kt) * 512 + lane * 8];
          }
#pragma unroll
          for (int i = 0; i < 2; ++i)
#pragma unroll
            for (int j = 0; j < 2; ++j)
              acc[i][j] = __builtin_amdgcn_mfma_f32_16x16x32_bf16(af[i], bfv[j], acc[i][j], 0, 0, 0);
        }
      }
#pragma unroll
      for (int i = 0; i < 2; ++i)
#pragma unroll
        for (int j = 0; j < 2; ++j)
#pragma unroll
          for (int e = 0; e < 4; ++e) {
            size_t row = MT * 64 + gA * 32 + i * 16 + q4 * 4 + e;
            size_t col = NT * 64 + gB * 32 + j * 16 + r16;
            p.Aalt[row * BH_ + col] = f2b(acc[i][j][e]);
          }
      gbar(p.BAR, (++phase) * 256u);
    }

    // ================= gates: 4 links/block, 2 pairs =================
    const bool enc = step < T_;
    const bool zf = (step == 0);
    const bool fc = (step >= T_ - 1);
    const bool wh = (step != 22);
    const int t = enc ? step : 0;
    const int s_dec = step - T_;
    const u16* ofr = (s_dec >= 0 && (s_dec & 1)) ? p.OFC1 : p.OFC0;
    u16* ofw;
    if (step == T_ - 1) ofw = p.OFC0;
    else ofw = (s_dec >= 0 && (s_dec & 1)) ? p.OFC0 : p.OFC1;
    const int s_out = step - (T_ - 1);

    for (int pair = 0; pair < 2; ++pair) {
      const int lp = wg4 * 4 + pair * 2;
      const int l = lp + li;
      __syncthreads();
      if (enc) {
        if (tid < 128) {
          int b = tid & 31, f = (tid >> 5) & 1, li2 = tid >> 6;
          din[(li2 * 2 + f) * 32 + b] = p.ENCIN[(((size_t)b * T_ + t) * 2 + f) * L_ + lp + li2];
        }
        __syncthreads();
      } else {
        if (tid < 256) ((uint4*)lWi)[tid] = ((const uint4*)(p.Wib + (size_t)lp * 1024))[tid];
        __syncthreads();
        const int pr = tid >> 3, sub = tid & 7;
        const int pb = pr >> 1, pl = pr & 1;
        const u16* orow = ofr + pb * 1024 + sub * 128;
        const u16* wrow = lWi + pl * 1024 + sub * 128;
        float s = 0.f;
#pragma unroll
        for (int j = 0; j < 16; ++j) {
          u16x8 o = *(const u16x8*)(orow + j * 8);
          u16x8 w = *(const u16x8*)(wrow + j * 8);
#pragma unroll
          for (int e = 0; e < 8; ++e) s += b2f(o[e]) * b2f(w[e]);
        }
        s += __shfl_xor(s, 1); s += __shfl_xor(s, 2); s += __shfl_xor(s, 4);
        if (sub == 0) { din[(pl * 2 + 0) * 32 + pb] = s; din[(pl * 2 + 1) * 32 + pb] = 0.f; }
        __syncthreads();
      }

      const u16* al = p.Aalt + (size_t)l * BH_;
      bf16x8 a[2];
      f32x4 aR[2] = {}, aZ[2] = {}, aN[2] = {};
      if (!zf) {
#pragma unroll
        for (int kt = 0; kt < 2; ++kt)
          a[kt] = *(const bf16x8*)&al[(mh * 16 + r16) * 64 + kt * 32 + q4 * 8];
        const size_t wbase = (size_t)l * 4096 + (size_t)(nh * 32 + r16) * 64 + q4 * 8;
#define DO_GATE(W, acc)                                                              \
        {                                                                            \
          bf16x8 w00 = *(const bf16x8*)&W[wbase];                                    \
          bf16x8 w01 = *(const bf16x8*)&W[wbase + 32];                               \
          bf16x8 w10 = *(const bf16x8*)&W[wbase + 1024];                             \
          bf16x8 w11 = *(const bf16x8*)&W[wbase + 1024 + 32];                        \
          acc[0] = __builtin_amdgcn_mfma_f32_16x16x32_bf16(a[0], w00, acc[0], 0, 0, 0);\
          acc[0] = __builtin_amdgcn_mfma_f32_16x16x32_bf16(a[1], w01, acc[0], 0, 0, 0);\
          acc[1] = __builtin_amdgcn_mfma_f32_16x16x32_bf16(a[0], w10, acc[1], 0, 0, 0);\
          acc[1] = __builtin_amdgcn_mfma_f32_16x16x32_bf16(a[1], w11, acc[1], 0, 0, 0);\
        }
        DO_GATE(p.WTr, aR)
        DO_GATE(p.WTz, aZ)
        DO_GATE(p.WTn, aN)
#undef DO_GATE
      }

      float i0v[4], i1v[4];
#pragma unroll
      for (int e = 0; e < 4; ++e) {
        const int bb = mh * 16 + q4 * 4 + e;
        i0v[e] = din[(li * 2 + 0) * 32 + bb];
        i1v[e] = enc ? din[(li * 2 + 1) * 32 + bb] : 0.f;
      }
#pragma unroll
      for (int ntl = 0; ntl < 2; ++ntl) {
        const int kk = nh * 32 + ntl * 16 + r16;
        const float vbr  = p.BRZ[l * 64 + kk];
        const float vbz  = p.BZZ[l * 64 + kk];
        const float vbnh = p.BNH[l * 64 + kk];
        const float vbni = p.BNI[l * 64 + kk];
        const float wr0 = p.Wir[l * 128 + kk], wr1 = p.Wir[l * 128 + 64 + kk];
        const float wz0 = p.Wiz[l * 128 + kk], wz1 = p.Wiz[l * 128 + 64 + kk];
        const float wn0 = p.Win[l * 128 + kk], wn1 = p.Win[l * 128 + 64 + kk];
#pragma unroll
        for (int e = 0; e < 4; ++e) {
          const int bb = mh * 16 + q4 * 4 + e;
          const float i0 = i0v[e], i1 = i1v[e];
          const float gr = aR[ntl][e] + vbr + i0 * wr0 + i1 * wr1;
          const float gz = aZ[ntl][e] + vbz + i0 * wz0 + i1 * wz1;
          const float gnh = aN[ntl][e] + vbnh;
          const float gni = i0 * wn0 + i1 * wn1 + vbni;
          const float rr = 1.f / (1.f + __expf(-gr));
          const float zz = 1.f / (1.f + __expf(-gz));
          const float xx = rr * gnh + gni;
          const float ex = __expf(2.f * xx);
          const float nn = (ex - 1.f) / (ex + 1.f);
          const float av = zf ? 0.f : b2f(al[bb * 64 + kk]);
          lout[(bb * 64 + kk) * 2 + li] = f2b((1.f - zz) * nn + zz * av);
        }
      }
      __syncthreads();

      if (wh) {   // HbT write (tiled fragment layout), this pair's 2 columns
        const int c0 = lp;
        const int ktile = c0 >> 6;
        const int cw = c0 & 63;
        const int kt2 = cw >> 5, q = (cw >> 3) & 3, e = cw & 7;
        for (int i = tid; i < BH_; i += 512) {
          int rw = i & 63, nt = i >> 6;
          int ci = (((rw >> 5) * 2 + ((rw >> 4) & 1)) * 2 + kt2) * 64 + (rw & 15) + q * 16;
          *(unsigned*)(p.HbT + (size_t)(nt * 16 + ktile) * 4096 + ci * 8 + e) =
              *(const unsigned*)&lout[i * 2];
        }
      }
      if (fc) {   // fc epilogue for this pair
        if (tid < 64) {
          const int b = tid & 31, li2 = tid >> 5;
          const int lf = lp + li2;
          float acc = 0.f;
          const float* wp = p.fcw + (size_t)lf * 64;
#pragma unroll 8
          for (int hh = 0; hh < 64; ++hh) {
            int hx = (hh + b) & 63;
            acc += b2f(lout[(b * 64 + hx) * 2 + li2]) * wp[hx];
          }
          acc += p.fcb[lf];
          p.outp[((size_t)b * HOR_ + s_out) * L_ + lf] = acc;
          ofw[(size_t)b * 1024 + lf] = f2b(acc);
        }
      }
    }
    if (step < 22) gbar(p.BAR, (++phase) * 256u);
  }
}

// ---------------- workspace map (bytes) ----------------
#define WS_HT    (size_t)0
#define WS_AALT  ((size_t)4 << 20)
#define WS_WHT   ((size_t)8 << 20)
#define WS_WIB   ((size_t)10 << 20)
#define WS_XB    ((size_t)12 << 20)
#define WS_WTR   ((size_t)14 << 20)
#define WS_WTZ   ((size_t)22 << 20)
#define WS_WTN   ((size_t)30 << 20)
#define WS_ENCIN ((size_t)38 << 20)
#define WS_OFC0  ((size_t)41 << 20)
#define WS_OFC1  (((size_t)41 << 20) + (64 << 10))
#define WS_BRZ   ((size_t)42 << 20)
#define WS_BZZ   (((size_t)42 << 20) + (256 << 10))
#define WS_BNH   (((size_t)42 << 20) + (512 << 10))
#define WS_BNI   (((size_t)42 << 20) + (768 << 10))
#define WS_BAR   ((size_t)43 << 20)

extern "C" void kernel_launch(void* const* d_in, const int* in_sizes, int n_in,
                              void* d_out, int out_size, void* d_ws, size_t ws_size,
                              hipStream_t stream) {
  const float* x   = (const float*)d_in[0];
  const float* Wi  = (const float*)d_in[1];
  const float* Wh  = (const float*)d_in[2];
  const float* Wrh = (const float*)d_in[3];
  const float* brh = (const float*)d_in[4];
  const float* Wri = (const float*)d_in[5];
  const float* bri = (const float*)d_in[6];
  const float* Wzh = (const float*)d_in[7];
  const float* bzh = (const float*)d_in[8];
  const float* Wzi = (const float*)d_in[9];
  const float* bzi = (const float*)d_in[10];
  const float* Wnh = (const float*)d_in[11];
  const float* bnh = (const float*)d_in[12];
  const float* Wni = (const float*)d_in[13];
  const float* bni = (const float*)d_in[14];
  const float* fcw = (const float*)d_in[15];
  const float* fcb = (const float*)d_in[16];
  float* out = (float*)d_out;

  char* ws = (char*)d_ws;
  u16*   HbT   = (u16*)(ws + WS_HT);
  u16*   Aalt  = (u16*)(ws + WS_AALT);
  u16*   WhT   = (u16*)(ws + WS_WHT);
  u16*   Wib   = (u16*)(ws + WS_WIB);
  u16*   xb    = (u16*)(ws + WS_XB);
  u16*   WTr   = (u16*)(ws + WS_WTR);
  u16*   WTz   = (u16*)(ws + WS_WTZ);
  u16*   WTn   = (u16*)(ws + WS_WTN);
  float* ENCIN = (float*)(ws + WS_ENCIN);
  u16*   OFC0  = (u16*)(ws + WS_OFC0);
  u16*   OFC1  = (u16*)(ws + WS_OFC1);
  float* BRZ   = (float*)(ws + WS_BRZ);
  float* BZZ   = (float*)(ws + WS_BZZ);
  float* BNH   = (float*)(ws + WS_BNH);
  float* BNI   = (float*)(ws + WS_BNI);
  unsigned* BAR = (unsigned*)(ws + WS_BAR);

  k_prep<<<5376, 256, 0, stream>>>(Wh, Wi, x, WhT, Wib, xb, Wrh, Wzh, Wnh, WTr, WTz, WTn,
                                   brh, bri, bzh, bzi, bnh, bni, BRZ, BZZ, BNH, BNI, BAR);
  k_gemm_nt<<<dim3(8, 12), 256, 0, stream>>>(xb, Wib, ENCIN, 1024, 1024);

  KP kp;
  kp.WhT = WhT; kp.HbT = HbT; kp.Aalt = Aalt;
  kp.WTr = WTr; kp.WTz = WTz; kp.WTn = WTn;
  kp.BRZ = BRZ; kp.BZZ = BZZ; kp.BNH = BNH; kp.BNI = BNI;
  kp.Wir = Wri; kp.Wiz = Wzi; kp.Win = Wni;
  kp.ENCIN = ENCIN; kp.Wib = Wib;
  kp.fcw = fcw; kp.fcb = fcb; kp.outp = out;
  kp.OFC0 = OFC0; kp.OFC1 = OFC1; kp.BAR = BAR;
  k_fused<<<256, 512, 0, stream>>>(kp);
}

// Round 17
// 777.575 us; speedup vs baseline: 4.3734x; 4.3734x over previous
//
#include <hip/hip_runtime.h>

#define T_ 12
#define L_ 1024
#define H_ 64
#define HOR_ 12
#define BH_ 2048

typedef unsigned short u16;
typedef __attribute__((ext_vector_type(8))) __bf16 bf16x8;
typedef __attribute__((ext_vector_type(8))) u16 u16x8;
typedef __attribute__((ext_vector_type(4))) float f32x4;

__device__ __forceinline__ u16 f2b(float f) {
  union { float f; unsigned u; } v; v.f = f;
  unsigned r = v.u + 0x7FFFu + ((v.u >> 16) & 1u);
  return (u16)(r >> 16);
}
__device__ __forceinline__ float b2f(u16 b) {
  union { unsigned u; float f; } v; v.u = ((unsigned)b) << 16;
  return v.f;
}
__device__ __forceinline__ void gld16(const void* g, void* l) {
  __builtin_amdgcn_global_load_lds((const __attribute__((address_space(1))) void*)g,
                                   (__attribute__((address_space(3))) void*)l, 16, 0, 0);
}

// 64x64 fragment-tile transform: (rw,cw) -> ci*8+e
//   ci = (((rw>>5)*2 + ((rw>>4)&1))*2 + (cw>>5))*64 + (rw&15) + ((cw>>3)&3)*16, e = cw&7

// ---- fused prep ----
__global__ __launch_bounds__(256) void k_prep(
    const float* __restrict__ Wh, const float* __restrict__ Wi, const float* __restrict__ x,
    u16* __restrict__ WhT, u16* __restrict__ Wib, u16* __restrict__ xb,
    const float* __restrict__ Wr, const float* __restrict__ Wz, const float* __restrict__ Wn,
    u16* __restrict__ WTr, u16* __restrict__ WTz, u16* __restrict__ WTn,
    const float* __restrict__ brh, const float* __restrict__ bri,
    const float* __restrict__ bzh, const float* __restrict__ bzi,
    const float* __restrict__ bnh, const float* __restrict__ bni,
    float* __restrict__ BRZ, float* __restrict__ BZZ,
    float* __restrict__ BNH, float* __restrict__ BNI) {
  __shared__ u16 lds[64][66];
  const int bid = blockIdx.x, tid = threadIdx.x;
  if (bid < 1792) {                       // ---- cvt: Wi | x ----
    const float* in; u16* out; int i;
    if (bid < 1024) { in = Wi; out = Wib; i = bid * 256 + tid; }
    else            { in = x;  out = xb;  i = (bid - 1024) * 256 + tid; }
    float4 v = ((const float4*)in)[i];
    ushort4 o;
    o.x = f2b(v.x); o.y = f2b(v.y); o.z = f2b(v.z); o.w = f2b(v.w);
    ((ushort4*)out)[i] = o;
  } else if (bid < 2048) {                // ---- WhT: tile Wh into fragment order ----
    const int q = bid - 1792;
    const int mt = q >> 4, kt = q & 15;
    u16* dst = WhT + (size_t)(mt * 16 + kt) * 4096;
#pragma unroll
    for (int j = 0; j < 2; ++j) {
      int ci = j * 256 + tid;
      int ln = ci & 63, kt2 = (ci >> 6) & 1, uu = (ci >> 7) & 1, gh = (ci >> 8) & 1;
      int rw = gh * 32 + uu * 16 + (ln & 15);
      int cw0 = kt2 * 32 + (ln >> 4) * 8;
      const float* src = Wh + (size_t)(mt * 64 + rw) * 1024 + kt * 64 + cw0;
      float4 v0 = *(const float4*)src, v1 = *(const float4*)(src + 4);
      u16x8 o;
      o[0] = f2b(v0.x); o[1] = f2b(v0.y); o[2] = f2b(v0.z); o[3] = f2b(v0.w);
      o[4] = f2b(v1.x); o[5] = f2b(v1.y); o[6] = f2b(v1.z); o[7] = f2b(v1.w);
      *(u16x8*)(dst + ci * 8) = o;
    }
  } else if (bid < 5120) {                // ---- transpose WT[l][k][h] = W[l][h][k] ----
    const int q = bid - 2048;
    const int sel = q >> 10, l = q & 1023;
    const float* w = (sel == 0 ? Wr : sel == 1 ? Wz : Wn) + (size_t)l * 4096;
    u16* t = (sel == 0 ? WTr : sel == 1 ? WTz : WTn) + (size_t)l * 4096;
#pragma unroll
    for (int j = 0; j < 16; ++j) {
      int idx = j * 256 + tid;
      lds[idx & 63][idx >> 6] = f2b(w[idx]);
    }
    __syncthreads();
#pragma unroll
    for (int j = 0; j < 2; ++j) {
      int w8 = j * 256 + tid;
      int k = w8 >> 3, h0 = (w8 & 7) * 8;
      u16x8 v;
#pragma unroll
      for (int e = 0; e < 8; ++e) v[e] = lds[k][h0 + e];
      *(u16x8*)(t + k * 64 + h0) = v;
    }
  } else {                                // ---- bias transpose+combine ----
    const int idx = (bid - 5120) * 256 + tid;
    const int l = idx >> 6, k = idx & 63;
    const int i = k * 1024 + l, o = l * 64 + k;
    BRZ[o] = brh[i] + bri[i];
    BZZ[o] = bzh[i] + bzi[i];
    BNH[o] = bnh[i];
    BNI[o] = bni[i];
  }
}

// -------- recurrent GEMM: 64x64 tile, tiled operands, DOUBLE-BUFFERED K-loop --------
__global__ __launch_bounds__(256, 2) void k_gemm_t(const u16* __restrict__ WhT,
                                                   const u16* __restrict__ HbT,
                                                   u16* __restrict__ C) {
  __shared__ __align__(16) u16 lA[2][4096];
  __shared__ __align__(16) u16 lB[2][4096];
  const int tid = threadIdx.x;
  const int lane = tid & 63, wv = tid >> 6;
  const int mt = blockIdx.y, nt = blockIdx.x;
  const int gA = wv >> 1, gB = wv & 1;
  const int r16 = lane & 15, q4 = lane >> 4;
  const u16* srcA = WhT + (size_t)mt * 16 * 4096;
  const u16* srcB = HbT + (size_t)nt * 16 * 4096;
  f32x4 acc[2][2] = {};
  // prologue: stage s=0 into buffer 0
#pragma unroll
  for (int j = 0; j < 2; ++j) {
    int ci = j * 256 + tid;
    gld16(srcA + ci * 8, lA[0] + ci * 8);
    gld16(srcB + ci * 8, lB[0] + ci * 8);
  }
  for (int s = 0; s < 16; ++s) {
    const int cur = s & 1;
    __syncthreads();                       // staging for s complete (vmcnt drained)
    if (s + 1 < 16) {                      // issue next-tile staging into other buffer
#pragma unroll
      for (int j = 0; j < 2; ++j) {
        int ci = j * 256 + tid;
        gld16(srcA + (size_t)(s + 1) * 4096 + ci * 8, lA[cur ^ 1] + ci * 8);
        gld16(srcB + (size_t)(s + 1) * 4096 + ci * 8, lB[cur ^ 1] + ci * 8);
      }
    }
#pragma unroll
    for (int kt = 0; kt < 2; ++kt) {
      bf16x8 af[2], bfv[2];
#pragma unroll
      for (int u = 0; u < 2; ++u) {
        af[u]  = *(const bf16x8*)&lA[cur][((gA * 2 + u) * 2 + kt) * 512 + lane * 8];
        bfv[u] = *(const bf16x8*)&lB[cur][((gB * 2 + u) * 2 + kt) * 512 + lane * 8];
      }
#pragma unroll
      for (int i = 0; i < 2; ++i)
#pragma unroll
        for (int j = 0; j < 2; ++j)
          acc[i][j] = __builtin_amdgcn_mfma_f32_16x16x32_bf16(af[i], bfv[j], acc[i][j], 0, 0, 0);
    }
  }
#pragma unroll
  for (int i = 0; i < 2; ++i)
#pragma unroll
    for (int j = 0; j < 2; ++j)
#pragma unroll
      for (int e = 0; e < 4; ++e) {
        size_t row = mt * 64 + gA * 32 + i * 16 + q4 * 4 + e;
        size_t col = nt * 64 + gB * 32 + j * 16 + r16;
        C[row * BH_ + col] = f2b(acc[i][j][e]);
      }
}

// -------- legacy 64x128 NT GEMM (one-time ENCIN), row-major operands --------
__global__ __launch_bounds__(256) void k_gemm_nt(const u16* __restrict__ A,
                                                 const u16* __restrict__ Bm,
                                                 float* __restrict__ C, int N, int K) {
  __shared__ __align__(16) u16 lA[64 * 64];
  __shared__ __align__(16) u16 lB[128 * 64];
  const int tid = threadIdx.x;
  const int lane = tid & 63, wv = tid >> 6;
  const int m0 = blockIdx.y * 64, n0 = blockIdx.x * 128;
  const int g2 = wv >> 1, gb = wv & 1;
  const int wm = g2 * 32, wn = gb * 64;
  const int r16 = lane & 15, q4 = lane >> 4;
  f32x4 acc[2][4] = {};
  for (int k0 = 0; k0 < K; k0 += 64) {
    __syncthreads();
#pragma unroll
    for (int j = 0; j < 2; ++j) {
      int ci = j * 256 + tid;
      int ln = ci & 63, kt = (ci >> 6) & 1, u = (ci >> 7) & 1, g = ci >> 8;
      int row = g * 32 + u * 16 + (ln & 15), c = kt * 4 + ((ln >> 4) & 3);
      gld16(A + (size_t)(m0 + row) * K + k0 + c * 8, lA + ci * 8);
    }
#pragma unroll
    for (int j = 0; j < 4; ++j) {
      int ci = j * 256 + tid;
      int ln = ci & 63, kt = (ci >> 6) & 1, u = (ci >> 7) & 3, g = ci >> 9;
      int row = g * 64 + u * 16 + (ln & 15), c = kt * 4 + ((ln >> 4) & 3);
      gld16(Bm + (size_t)(n0 + row) * K + k0 + c * 8, lB + ci * 8);
    }
    __syncthreads();
#pragma unroll
    for (int kt = 0; kt < 2; ++kt) {
      bf16x8 af[2], bfv[4];
#pragma unroll
      for (int u = 0; u < 2; ++u)
        af[u] = *(const bf16x8*)&lA[((g2 * 2 + u) * 2 + kt) * 512 + lane * 8];
#pragma unroll
      for (int u = 0; u < 4; ++u)
        bfv[u] = *(const bf16x8*)&lB[((gb * 4 + u) * 2 + kt) * 512 + lane * 8];
#pragma unroll
      for (int i = 0; i < 2; ++i)
#pragma unroll
        for (int j = 0; j < 4; ++j)
          acc[i][j] = __builtin_amdgcn_mfma_f32_16x16x32_bf16(af[i], bfv[j], acc[i][j], 0, 0, 0);
    }
  }
#pragma unroll
  for (int i = 0; i < 2; ++i)
#pragma unroll
    for (int j = 0; j < 4; ++j)
#pragma unroll
      for (int e = 0; e < 4; ++e) {
        size_t row = m0 + wm + i * 16 + q4 * 4 + e;
        size_t col = n0 + wn + j * 16 + r16;
        C[row * N + col] = acc[i][j][e];
      }
}

// -------- gates (+fused decoder-input-attn prologue, +fused fc epilogue) --------
template <int ENC, int Z, int FC, int WH>
__global__ __launch_bounds__(512, 4) void k_gates(
    const u16* __restrict__ Aalt, const u16* __restrict__ WTr, const u16* __restrict__ WTz,
    const u16* __restrict__ WTn, const float* __restrict__ BRZ, const float* __restrict__ BZZ,
    const float* __restrict__ BNH, const float* __restrict__ BNI,
    const float* __restrict__ Wir, const float* __restrict__ Wiz, const float* __restrict__ Win,
    const float* __restrict__ inp, const u16* __restrict__ OUTFC_r, const u16* __restrict__ Wib,
    const float* __restrict__ fcw, const float* __restrict__ fcb,
    float* __restrict__ outp, u16* __restrict__ OUTFC_w, int t, int s_out,
    u16* __restrict__ HbT) {
  __shared__ __align__(8) u16 lout[BH_ * 2];
  __shared__ __align__(16) u16 lWi[2048];
  __shared__ float din[2][2][32];       // [li][f][b]
  const int tid = threadIdx.x;
  const int lane = tid & 63, wv = tid >> 6;
  const int li = wv >> 2, mh = (wv >> 1) & 1, nh = wv & 1;
  const int bid = blockIdx.x;
  const int wg = (bid & 7) * 64 + (bid >> 3);   // chunked XCD map
  const int l = wg * 2 + li;
  const int r16 = lane & 15, q4 = lane >> 4;

  if (ENC) {
    if (tid < 128) {
      int b = tid & 31, f = (tid >> 5) & 1, li2 = tid >> 6;
      din[li2][f][b] = inp[(((size_t)b * T_ + t) * 2 + f) * L_ + wg * 2 + li2];
    }
    __syncthreads();
  } else {
    if (tid < 256) ((uint4*)lWi)[tid] = ((const uint4*)(Wib + (size_t)(wg * 2) * 1024))[tid];
    __syncthreads();
    const int pair = tid >> 3, sub = tid & 7;
    const int pb = pair >> 1, pl = pair & 1;
    const u16* orow = OUTFC_r + pb * 1024 + sub * 128;
    const u16* wrow = lWi + pl * 1024 + sub * 128;
    float s = 0.f;
#pragma unroll
    for (int j = 0; j < 16; ++j) {
      u16x8 o = *(const u16x8*)(orow + j * 8);
      u16x8 w = *(const u16x8*)(wrow + j * 8);
#pragma unroll
      for (int e = 0; e < 8; ++e) s += b2f(o[e]) * b2f(w[e]);
    }
    s += __shfl_xor(s, 1); s += __shfl_xor(s, 2); s += __shfl_xor(s, 4);
    if (sub == 0) { din[pl][0][pb] = s; din[pl][1][pb] = 0.f; }
    __syncthreads();
  }

  const u16* al = Aalt + (size_t)l * BH_;
  bf16x8 a[2];
  f32x4 aR[2] = {}, aZ[2] = {}, aN[2] = {};
  if (Z == 0) {
#pragma unroll
    for (int kt = 0; kt < 2; ++kt)
      a[kt] = *(const bf16x8*)&al[(mh * 16 + r16) * 64 + kt * 32 + q4 * 8];
    const size_t wbase = (size_t)l * 4096 + (size_t)(nh * 32 + r16) * 64 + q4 * 8;
#define DO_GATE(W, acc)                                                              \
    {                                                                                \
      bf16x8 w00 = *(const bf16x8*)&W[wbase];                                        \
      bf16x8 w01 = *(const bf16x8*)&W[wbase + 32];                                   \
      bf16x8 w10 = *(const bf16x8*)&W[wbase + 1024];                                 \
      bf16x8 w11 = *(const bf16x8*)&W[wbase + 1024 + 32];                            \
      acc[0] = __builtin_amdgcn_mfma_f32_16x16x32_bf16(a[0], w00, acc[0], 0, 0, 0);  \
      acc[0] = __builtin_amdgcn_mfma_f32_16x16x32_bf16(a[1], w01, acc[0], 0, 0, 0);  \
      acc[1] = __builtin_amdgcn_mfma_f32_16x16x32_bf16(a[0], w10, acc[1], 0, 0, 0);  \
      acc[1] = __builtin_amdgcn_mfma_f32_16x16x32_bf16(a[1], w11, acc[1], 0, 0, 0);  \
    }
    DO_GATE(WTr, aR)
    DO_GATE(WTz, aZ)
    DO_GATE(WTn, aN)
#undef DO_GATE
  }

  float i0v[4], i1v[4];
#pragma unroll
  for (int e = 0; e < 4; ++e) {
    const int bb = mh * 16 + q4 * 4 + e;
    i0v[e] = din[li][0][bb];
    i1v[e] = ENC ? din[li][1][bb] : 0.f;
  }
#pragma unroll
  for (int ntl = 0; ntl < 2; ++ntl) {
    const int kk = nh * 32 + ntl * 16 + r16;
    const float vbr  = BRZ[l * 64 + kk];
    const float vbz  = BZZ[l * 64 + kk];
    const float vbnh = BNH[l * 64 + kk];
    const float vbni = BNI[l * 64 + kk];
    const float wr0 = Wir[l * 128 + kk], wr1 = Wir[l * 128 + 64 + kk];
    const float wz0 = Wiz[l * 128 + kk], wz1 = Wiz[l * 128 + 64 + kk];
    const float wn0 = Win[l * 128 + kk], wn1 = Win[l * 128 + 64 + kk];
#pragma unroll
    for (int e = 0; e < 4; ++e) {
      const int bb = mh * 16 + q4 * 4 + e;
      const float i0 = i0v[e], i1 = i1v[e];
      const float gr = aR[ntl][e] + vbr + i0 * wr0 + i1 * wr1;
      const float gz = aZ[ntl][e] + vbz + i0 * wz0 + i1 * wz1;
      const float gnh = aN[ntl][e] + vbnh;
      const float gni = i0 * wn0 + i1 * wn1 + vbni;
      const float rr = 1.f / (1.f + __expf(-gr));
      const float zz = 1.f / (1.f + __expf(-gz));
      const float xx = rr * gnh + gni;
      const float ex = __expf(2.f * xx);
      const float nn = (ex - 1.f) / (ex + 1.f);
      const float av = Z ? 0.f : b2f(al[bb * 64 + kk]);
      lout[(bb * 64 + kk) * 2 + li] = f2b((1.f - zz) * nn + zz * av);
    }
  }
  __syncthreads();

  if (WH) {   // ---- HbT write: tiled fragment layout ----
    const int c0 = wg * 2;
    const int ktile = c0 >> 6;
    const int cw = c0 & 63;
    const int kt2 = cw >> 5, q = (cw >> 3) & 3, e = cw & 7;
    for (int i = tid; i < BH_; i += 512) {
      int rw = i & 63, nt = i >> 6;
      int ci = (((rw >> 5) * 2 + ((rw >> 4) & 1)) * 2 + kt2) * 64 + (rw & 15) + q * 16;
      *(unsigned*)(HbT + (size_t)(nt * 16 + ktile) * 4096 + ci * 8 + e) =
          *(const unsigned*)&lout[i * 2];
    }
  }

  if (FC) {
    if (tid < 64) {
      const int b = tid & 31, li2 = tid >> 5;
      const int lf = wg * 2 + li2;
      float acc = 0.f;
      const float* wp = fcw + (size_t)lf * 64;
#pragma unroll 8
      for (int hh = 0; hh < 64; ++hh) {
        int h = (hh + b) & 63;
        acc += b2f(lout[(b * 64 + h) * 2 + li2]) * wp[h];
      }
      acc += fcb[lf];
      outp[((size_t)b * HOR_ + s_out) * L_ + lf] = acc;
      OUTFC_w[(size_t)b * 1024 + lf] = f2b(acc);
    }
  }
}

// ---------------- workspace map (bytes) — total ~43 MB ----------------
#define WS_HT    (size_t)0          // bf16 HbT tiled [32][16][4096]   4 MB
#define WS_AALT  ((size_t)4 << 20)  // bf16 A[l][bh]                   4 MB
#define WS_WHT   ((size_t)8 << 20)  // bf16 WhT tiled [16][16][4096]   2 MB
#define WS_WIB   ((size_t)10 << 20) // bf16 Wi[m][l] row-major         2 MB
#define WS_XB    ((size_t)12 << 20) // bf16 x rows (b,t,f)[l]          1.5 MB
#define WS_WTR   ((size_t)14 << 20) // bf16 WT_r[l][k][h]              8 MB
#define WS_WTZ   ((size_t)22 << 20)
#define WS_WTN   ((size_t)30 << 20)
#define WS_ENCIN ((size_t)38 << 20) // f32 ENCIN[(b,t,f)][m]           3 MB
#define WS_OFC0  ((size_t)41 << 20) // bf16 OUTFC ping                 64 KB
#define WS_OFC1  (((size_t)41 << 20) + (64 << 10))
#define WS_BRZ   ((size_t)42 << 20) // f32 [1024][64]                  256 KB
#define WS_BZZ   (((size_t)42 << 20) + (256 << 10))
#define WS_BNH   (((size_t)42 << 20) + (512 << 10))
#define WS_BNI   (((size_t)42 << 20) + (768 << 10))

extern "C" void kernel_launch(void* const* d_in, const int* in_sizes, int n_in,
                              void* d_out, int out_size, void* d_ws, size_t ws_size,
                              hipStream_t stream) {
  const float* x   = (const float*)d_in[0];
  const float* Wi  = (const float*)d_in[1];
  const float* Wh  = (const float*)d_in[2];
  const float* Wrh = (const float*)d_in[3];
  const float* brh = (const float*)d_in[4];
  const float* Wri = (const float*)d_in[5];
  const float* bri = (const float*)d_in[6];
  const float* Wzh = (const float*)d_in[7];
  const float* bzh = (const float*)d_in[8];
  const float* Wzi = (const float*)d_in[9];
  const float* bzi = (const float*)d_in[10];
  const float* Wnh = (const float*)d_in[11];
  const float* bnh = (const float*)d_in[12];
  const float* Wni = (const float*)d_in[13];
  const float* bni = (const float*)d_in[14];
  const float* fcw = (const float*)d_in[15];
  const float* fcb = (const float*)d_in[16];
  float* out = (float*)d_out;

  char* ws = (char*)d_ws;
  u16*   HbT   = (u16*)(ws + WS_HT);
  u16*   Aalt  = (u16*)(ws + WS_AALT);
  u16*   WhT   = (u16*)(ws + WS_WHT);
  u16*   Wib   = (u16*)(ws + WS_WIB);
  u16*   xb    = (u16*)(ws + WS_XB);
  u16*   WTr   = (u16*)(ws + WS_WTR);
  u16*   WTz   = (u16*)(ws + WS_WTZ);
  u16*   WTn   = (u16*)(ws + WS_WTN);
  float* ENCIN = (float*)(ws + WS_ENCIN);
  u16*   OFC0  = (u16*)(ws + WS_OFC0);
  u16*   OFC1  = (u16*)(ws + WS_OFC1);
  float* BRZ   = (float*)(ws + WS_BRZ);
  float* BZZ   = (float*)(ws + WS_BZZ);
  float* BNH   = (float*)(ws + WS_BNH);
  float* BNI   = (float*)(ws + WS_BNI);

  k_prep<<<5376, 256, 0, stream>>>(Wh, Wi, x, WhT, Wib, xb, Wrh, Wzh, Wnh, WTr, WTz, WTn,
                                   brh, bri, bzh, bzi, bnh, bni, BRZ, BZZ, BNH, BNI);
  // all-timestep encoder input attn: ENCIN[(b,t,f)][m] = sum_l x * Wi[m,l]
  k_gemm_nt<<<dim3(8, 12), 256, 0, stream>>>(xb, Wib, ENCIN, 1024, 1024);

  // encoder: t=0 has H=0 -> skip hidden-attn GEMM, Z-path gates
  k_gates<1, 1, 0, 1><<<512, 512, 0, stream>>>(Aalt, WTr, WTz, WTn, BRZ, BZZ, BNH, BNI,
                                               Wri, Wzi, Wni, ENCIN, OFC0, Wib, fcw, fcb,
                                               out, OFC0, 0, 0, HbT);
  for (int t = 1; t < T_; ++t) {
    k_gemm_t<<<dim3(32, 16), 256, 0, stream>>>(WhT, HbT, Aalt);
    if (t < T_ - 1)
      k_gates<1, 0, 0, 1><<<512, 512, 0, stream>>>(Aalt, WTr, WTz, WTn, BRZ, BZZ, BNH, BNI,
                                                   Wri, Wzi, Wni, ENCIN, OFC0, Wib, fcw, fcb,
                                                   out, OFC0, t, 0, HbT);
    else
      k_gates<1, 0, 1, 1><<<512, 512, 0, stream>>>(Aalt, WTr, WTz, WTn, BRZ, BZZ, BNH, BNI,
                                                   Wri, Wzi, Wni, ENCIN, OFC0, Wib, fcw, fcb,
                                                   out, OFC0, t, 0, HbT);
  }
  // decoder: s = 0..10 (step 11's hidden update is unused)
  for (int s = 0; s <= 10; ++s) {
    const u16* ofr = (s & 1) ? OFC1 : OFC0;
    u16*       ofw = (s & 1) ? OFC0 : OFC1;
    k_gemm_t<<<dim3(32, 16), 256, 0, stream>>>(WhT, HbT, Aalt);
    if (s < 10)
      k_gates<0, 0, 1, 1><<<512, 512, 0, stream>>>(Aalt, WTr, WTz, WTn, BRZ, BZZ, BNH, BNI,
                                                   Wri, Wzi, Wni, ENCIN, ofr, Wib, fcw, fcb,
                                                   out, ofw, 0, s + 1, HbT);
    else
      k_gates<0, 0, 1, 0><<<512, 512, 0, stream>>>(Aalt, WTr, WTz, WTn, BRZ, BZZ, BNH, BNI,
                                                   Wri, Wzi, Wni, ENCIN, ofr, Wib, fcw, fcb,
                                                   out, ofw, 0, s + 1, HbT);
  }
}

// Round 18
// 688.818 us; speedup vs baseline: 4.9369x; 1.1289x over previous
//
#include <hip/hip_runtime.h>

#define T_ 12
#define L_ 1024
#define H_ 64
#define HOR_ 12
#define BH_ 2048

typedef unsigned short u16;
typedef __attribute__((ext_vector_type(8))) __bf16 bf16x8;
typedef __attribute__((ext_vector_type(8))) u16 u16x8;
typedef __attribute__((ext_vector_type(4))) float f32x4;

__device__ __forceinline__ u16 f2b(float f) {
  union { float f; unsigned u; } v; v.f = f;
  unsigned r = v.u + 0x7FFFu + ((v.u >> 16) & 1u);
  return (u16)(r >> 16);
}
__device__ __forceinline__ float b2f(u16 b) {
  union { unsigned u; float f; } v; v.u = ((unsigned)b) << 16;
  return v.f;
}
__device__ __forceinline__ void gld16(const void* g, void* l) {
  __builtin_amdgcn_global_load_lds((const __attribute__((address_space(1))) void*)g,
                                   (__attribute__((address_space(3))) void*)l, 16, 0, 0);
}

// 64x64 fragment-tile transform: (rw,cw) -> ci*8+e
//   ci = (((rw>>5)*2 + ((rw>>4)&1))*2 + (cw>>5))*64 + (rw&15) + ((cw>>3)&3)*16, e = cw&7

// ---- fused prep ----
__global__ __launch_bounds__(256) void k_prep(
    const float* __restrict__ Wh, const float* __restrict__ Wi, const float* __restrict__ x,
    u16* __restrict__ WhT, u16* __restrict__ Wib, u16* __restrict__ xb,
    const float* __restrict__ Wr, const float* __restrict__ Wz, const float* __restrict__ Wn,
    u16* __restrict__ WTr, u16* __restrict__ WTz, u16* __restrict__ WTn,
    const float* __restrict__ brh, const float* __restrict__ bri,
    const float* __restrict__ bzh, const float* __restrict__ bzi,
    const float* __restrict__ bnh, const float* __restrict__ bni,
    float* __restrict__ BRZ, float* __restrict__ BZZ,
    float* __restrict__ BNH, float* __restrict__ BNI) {
  __shared__ u16 lds[64][66];
  const int bid = blockIdx.x, tid = threadIdx.x;
  if (bid < 1792) {                       // ---- cvt: Wi | x ----
    const float* in; u16* out; int i;
    if (bid < 1024) { in = Wi; out = Wib; i = bid * 256 + tid; }
    else            { in = x;  out = xb;  i = (bid - 1024) * 256 + tid; }
    float4 v = ((const float4*)in)[i];
    ushort4 o;
    o.x = f2b(v.x); o.y = f2b(v.y); o.z = f2b(v.z); o.w = f2b(v.w);
    ((ushort4*)out)[i] = o;
  } else if (bid < 2048) {                // ---- WhT: tile Wh into fragment order ----
    const int q = bid - 1792;
    const int mt = q >> 4, kt = q & 15;
    u16* dst = WhT + (size_t)(mt * 16 + kt) * 4096;
#pragma unroll
    for (int j = 0; j < 2; ++j) {
      int ci = j * 256 + tid;
      int ln = ci & 63, kt2 = (ci >> 6) & 1, uu = (ci >> 7) & 1, gh = (ci >> 8) & 1;
      int rw = gh * 32 + uu * 16 + (ln & 15);
      int cw0 = kt2 * 32 + (ln >> 4) * 8;
      const float* src = Wh + (size_t)(mt * 64 + rw) * 1024 + kt * 64 + cw0;
      float4 v0 = *(const float4*)src, v1 = *(const float4*)(src + 4);
      u16x8 o;
      o[0] = f2b(v0.x); o[1] = f2b(v0.y); o[2] = f2b(v0.z); o[3] = f2b(v0.w);
      o[4] = f2b(v1.x); o[5] = f2b(v1.y); o[6] = f2b(v1.z); o[7] = f2b(v1.w);
      *(u16x8*)(dst + ci * 8) = o;
    }
  } else if (bid < 5120) {                // ---- transpose WT[l][k][h] = W[l][h][k] ----
    const int q = bid - 2048;
    const int sel = q >> 10, l = q & 1023;
    const float* w = (sel == 0 ? Wr : sel == 1 ? Wz : Wn) + (size_t)l * 4096;
    u16* t = (sel == 0 ? WTr : sel == 1 ? WTz : WTn) + (size_t)l * 4096;
#pragma unroll
    for (int j = 0; j < 16; ++j) {
      int idx = j * 256 + tid;
      lds[idx & 63][idx >> 6] = f2b(w[idx]);
    }
    __syncthreads();
#pragma unroll
    for (int j = 0; j < 2; ++j) {
      int w8 = j * 256 + tid;
      int k = w8 >> 3, h0 = (w8 & 7) * 8;
      u16x8 v;
#pragma unroll
      for (int e = 0; e < 8; ++e) v[e] = lds[k][h0 + e];
      *(u16x8*)(t + k * 64 + h0) = v;
    }
  } else {                                // ---- bias transpose+combine ----
    const int idx = (bid - 5120) * 256 + tid;
    const int l = idx >> 6, k = idx & 63;
    const int i = k * 1024 + l, o = l * 64 + k;
    BRZ[o] = brh[i] + bri[i];
    BZZ[o] = bzh[i] + bzi[i];
    BNH[o] = bnh[i];
    BNI[o] = bni[i];
  }
}

// -------- recurrent GEMM: 64x64 tile, tiled operands, single-buffered,
// -------- TWO K-subtiles staged per barrier pair (16 barriers instead of 32)
__global__ __launch_bounds__(256, 2) void k_gemm_t(const u16* __restrict__ WhT,
                                                   const u16* __restrict__ HbT,
                                                   u16* __restrict__ C) {
  __shared__ __align__(16) u16 lA[8192];   // 2 subtiles x 8 KB
  __shared__ __align__(16) u16 lB[8192];
  const int tid = threadIdx.x;
  const int lane = tid & 63, wv = tid >> 6;
  const int mt = blockIdx.y, nt = blockIdx.x;
  const int gA = wv >> 1, gB = wv & 1;
  const int r16 = lane & 15, q4 = lane >> 4;
  const u16* srcA = WhT + (size_t)mt * 16 * 4096;
  const u16* srcB = HbT + (size_t)nt * 16 * 4096;
  f32x4 acc[2][2] = {};
  for (int s = 0; s < 16; s += 2) {
    __syncthreads();
#pragma unroll
    for (int j = 0; j < 4; ++j) {          // 1024 chunks each of A,B (4/thread)
      int ci = j * 256 + tid;
      gld16(srcA + (size_t)s * 4096 + ci * 8, lA + ci * 8);
      gld16(srcB + (size_t)s * 4096 + ci * 8, lB + ci * 8);
    }
    __syncthreads();
#pragma unroll
    for (int ss = 0; ss < 2; ++ss) {
#pragma unroll
      for (int kt = 0; kt < 2; ++kt) {
        bf16x8 af[2], bfv[2];
#pragma unroll
        for (int u = 0; u < 2; ++u) {
          af[u]  = *(const bf16x8*)&lA[ss * 4096 + ((gA * 2 + u) * 2 + kt) * 512 + lane * 8];
          bfv[u] = *(const bf16x8*)&lB[ss * 4096 + ((gB * 2 + u) * 2 + kt) * 512 + lane * 8];
        }
#pragma unroll
        for (int i = 0; i < 2; ++i)
#pragma unroll
          for (int j = 0; j < 2; ++j)
            acc[i][j] = __builtin_amdgcn_mfma_f32_16x16x32_bf16(af[i], bfv[j], acc[i][j], 0, 0, 0);
      }
    }
  }
#pragma unroll
  for (int i = 0; i < 2; ++i)
#pragma unroll
    for (int j = 0; j < 2; ++j)
#pragma unroll
      for (int e = 0; e < 4; ++e) {
        size_t row = mt * 64 + gA * 32 + i * 16 + q4 * 4 + e;
        size_t col = nt * 64 + gB * 32 + j * 16 + r16;
        C[row * BH_ + col] = f2b(acc[i][j][e]);
      }
}

// -------- legacy 64x128 NT GEMM (one-time ENCIN), row-major operands --------
__global__ __launch_bounds__(256) void k_gemm_nt(const u16* __restrict__ A,
                                                 const u16* __restrict__ Bm,
                                                 float* __restrict__ C, int N, int K) {
  __shared__ __align__(16) u16 lA[64 * 64];
  __shared__ __align__(16) u16 lB[128 * 64];
  const int tid = threadIdx.x;
  const int lane = tid & 63, wv = tid >> 6;
  const int m0 = blockIdx.y * 64, n0 = blockIdx.x * 128;
  const int g2 = wv >> 1, gb = wv & 1;
  const int wm = g2 * 32, wn = gb * 64;
  const int r16 = lane & 15, q4 = lane >> 4;
  f32x4 acc[2][4] = {};
  for (int k0 = 0; k0 < K; k0 += 64) {
    __syncthreads();
#pragma unroll
    for (int j = 0; j < 2; ++j) {
      int ci = j * 256 + tid;
      int ln = ci & 63, kt = (ci >> 6) & 1, u = (ci >> 7) & 1, g = ci >> 8;
      int row = g * 32 + u * 16 + (ln & 15), c = kt * 4 + ((ln >> 4) & 3);
      gld16(A + (size_t)(m0 + row) * K + k0 + c * 8, lA + ci * 8);
    }
#pragma unroll
    for (int j = 0; j < 4; ++j) {
      int ci = j * 256 + tid;
      int ln = ci & 63, kt = (ci >> 6) & 1, u = (ci >> 7) & 3, g = ci >> 9;
      int row = g * 64 + u * 16 + (ln & 15), c = kt * 4 + ((ln >> 4) & 3);
      gld16(Bm + (size_t)(n0 + row) * K + k0 + c * 8, lB + ci * 8);
    }
    __syncthreads();
#pragma unroll
    for (int kt = 0; kt < 2; ++kt) {
      bf16x8 af[2], bfv[4];
#pragma unroll
      for (int u = 0; u < 2; ++u)
        af[u] = *(const bf16x8*)&lA[((g2 * 2 + u) * 2 + kt) * 512 + lane * 8];
#pragma unroll
      for (int u = 0; u < 4; ++u)
        bfv[u] = *(const bf16x8*)&lB[((gb * 4 + u) * 2 + kt) * 512 + lane * 8];
#pragma unroll
      for (int i = 0; i < 2; ++i)
#pragma unroll
        for (int j = 0; j < 4; ++j)
          acc[i][j] = __builtin_amdgcn_mfma_f32_16x16x32_bf16(af[i], bfv[j], acc[i][j], 0, 0, 0);
    }
  }
#pragma unroll
  for (int i = 0; i < 2; ++i)
#pragma unroll
    for (int j = 0; j < 4; ++j)
#pragma unroll
      for (int e = 0; e < 4; ++e) {
        size_t row = m0 + wm + i * 16 + q4 * 4 + e;
        size_t col = n0 + wn + j * 16 + r16;
        C[row * N + col] = acc[i][j][e];
      }
}

// -------- gates (+fused decoder-input-attn prologue, +fused fc epilogue) --------
template <int ENC, int Z, int FC, int WH>
__global__ __launch_bounds__(512, 4) void k_gates(
    const u16* __restrict__ Aalt, const u16* __restrict__ WTr, const u16* __restrict__ WTz,
    const u16* __restrict__ WTn, const float* __restrict__ BRZ, const float* __restrict__ BZZ,
    const float* __restrict__ BNH, const float* __restrict__ BNI,
    const float* __restrict__ Wir, const float* __restrict__ Wiz, const float* __restrict__ Win,
    const float* __restrict__ inp, const u16* __restrict__ OUTFC_r, const u16* __restrict__ Wib,
    const float* __restrict__ fcw, const float* __restrict__ fcb,
    float* __restrict__ outp, u16* __restrict__ OUTFC_w, int t, int s_out,
    u16* __restrict__ HbT) {
  __shared__ __align__(8) u16 lout[BH_ * 2];
  __shared__ __align__(16) u16 lWi[2048];
  __shared__ float din[2][2][32];       // [li][f][b]
  const int tid = threadIdx.x;
  const int lane = tid & 63, wv = tid >> 6;
  const int li = wv >> 2, mh = (wv >> 1) & 1, nh = wv & 1;
  const int bid = blockIdx.x;
  const int wg = (bid & 7) * 64 + (bid >> 3);   // chunked XCD map
  const int l = wg * 2 + li;
  const int r16 = lane & 15, q4 = lane >> 4;

  if (ENC) {
    if (tid < 128) {
      int b = tid & 31, f = (tid >> 5) & 1, li2 = tid >> 6;
      din[li2][f][b] = inp[(((size_t)b * T_ + t) * 2 + f) * L_ + wg * 2 + li2];
    }
    __syncthreads();
  } else {
    if (tid < 256) ((uint4*)lWi)[tid] = ((const uint4*)(Wib + (size_t)(wg * 2) * 1024))[tid];
    __syncthreads();
    const int pair = tid >> 3, sub = tid & 7;
    const int pb = pair >> 1, pl = pair & 1;
    const u16* orow = OUTFC_r + pb * 1024 + sub * 128;
    const u16* wrow = lWi + pl * 1024 + sub * 128;
    float s = 0.f;
#pragma unroll
    for (int j = 0; j < 16; ++j) {
      u16x8 o = *(const u16x8*)(orow + j * 8);
      u16x8 w = *(const u16x8*)(wrow + j * 8);
#pragma unroll
      for (int e = 0; e < 8; ++e) s += b2f(o[e]) * b2f(w[e]);
    }
    s += __shfl_xor(s, 1); s += __shfl_xor(s, 2); s += __shfl_xor(s, 4);
    if (sub == 0) { din[pl][0][pb] = s; din[pl][1][pb] = 0.f; }
    __syncthreads();
  }

  const u16* al = Aalt + (size_t)l * BH_;
  bf16x8 a[2];
  f32x4 aR[2] = {}, aZ[2] = {}, aN[2] = {};
  if (Z == 0) {
#pragma unroll
    for (int kt = 0; kt < 2; ++kt)
      a[kt] = *(const bf16x8*)&al[(mh * 16 + r16) * 64 + kt * 32 + q4 * 8];
    const size_t wbase = (size_t)l * 4096 + (size_t)(nh * 32 + r16) * 64 + q4 * 8;
#define DO_GATE(W, acc)                                                              \
    {                                                                                \
      bf16x8 w00 = *(const bf16x8*)&W[wbase];                                        \
      bf16x8 w01 = *(const bf16x8*)&W[wbase + 32];                                   \
      bf16x8 w10 = *(const bf16x8*)&W[wbase + 1024];                                 \
      bf16x8 w11 = *(const bf16x8*)&W[wbase + 1024 + 32];                            \
      acc[0] = __builtin_amdgcn_mfma_f32_16x16x32_bf16(a[0], w00, acc[0], 0, 0, 0);  \
      acc[0] = __builtin_amdgcn_mfma_f32_16x16x32_bf16(a[1], w01, acc[0], 0, 0, 0);  \
      acc[1] = __builtin_amdgcn_mfma_f32_16x16x32_bf16(a[0], w10, acc[1], 0, 0, 0);  \
      acc[1] = __builtin_amdgcn_mfma_f32_16x16x32_bf16(a[1], w11, acc[1], 0, 0, 0);  \
    }
    DO_GATE(WTr, aR)
    DO_GATE(WTz, aZ)
    DO_GATE(WTn, aN)
#undef DO_GATE
  }

  float i0v[4], i1v[4];
#pragma unroll
  for (int e = 0; e < 4; ++e) {
    const int bb = mh * 16 + q4 * 4 + e;
    i0v[e] = din[li][0][bb];
    i1v[e] = ENC ? din[li][1][bb] : 0.f;
  }
#pragma unroll
  for (int ntl = 0; ntl < 2; ++ntl) {
    const int kk = nh * 32 + ntl * 16 + r16;
    const float vbr  = BRZ[l * 64 + kk];
    const float vbz  = BZZ[l * 64 + kk];
    const float vbnh = BNH[l * 64 + kk];
    const float vbni = BNI[l * 64 + kk];
    const float wr0 = Wir[l * 128 + kk], wr1 = Wir[l * 128 + 64 + kk];
    const float wz0 = Wiz[l * 128 + kk], wz1 = Wiz[l * 128 + 64 + kk];
    const float wn0 = Win[l * 128 + kk], wn1 = Win[l * 128 + 64 + kk];
#pragma unroll
    for (int e = 0; e < 4; ++e) {
      const int bb = mh * 16 + q4 * 4 + e;
      const float i0 = i0v[e], i1 = i1v[e];
      const float gr = aR[ntl][e] + vbr + i0 * wr0 + i1 * wr1;
      const float gz = aZ[ntl][e] + vbz + i0 * wz0 + i1 * wz1;
      const float gnh = aN[ntl][e] + vbnh;
      const float gni = i0 * wn0 + i1 * wn1 + vbni;
      const float rr = 1.f / (1.f + __expf(-gr));
      const float zz = 1.f / (1.f + __expf(-gz));
      const float xx = rr * gnh + gni;
      const float ex = __expf(2.f * xx);
      const float nn = (ex - 1.f) / (ex + 1.f);
      const float av = Z ? 0.f : b2f(al[bb * 64 + kk]);
      lout[(bb * 64 + kk) * 2 + li] = f2b((1.f - zz) * nn + zz * av);
    }
  }
  __syncthreads();

  if (WH) {   // ---- HbT write: tiled fragment layout ----
    const int c0 = wg * 2;
    const int ktile = c0 >> 6;
    const int cw = c0 & 63;
    const int kt2 = cw >> 5, q = (cw >> 3) & 3, e = cw & 7;
    for (int i = tid; i < BH_; i += 512) {
      int rw = i & 63, nt = i >> 6;
      int ci = (((rw >> 5) * 2 + ((rw >> 4) & 1)) * 2 + kt2) * 64 + (rw & 15) + q * 16;
      *(unsigned*)(HbT + (size_t)(nt * 16 + ktile) * 4096 + ci * 8 + e) =
          *(const unsigned*)&lout[i * 2];
    }
  }

  if (FC) {
    if (tid < 64) {
      const int b = tid & 31, li2 = tid >> 5;
      const int lf = wg * 2 + li2;
      float acc = 0.f;
      const float* wp = fcw + (size_t)lf * 64;
#pragma unroll 8
      for (int hh = 0; hh < 64; ++hh) {
        int h = (hh + b) & 63;
        acc += b2f(lout[(b * 64 + h) * 2 + li2]) * wp[h];
      }
      acc += fcb[lf];
      outp[((size_t)b * HOR_ + s_out) * L_ + lf] = acc;
      OUTFC_w[(size_t)b * 1024 + lf] = f2b(acc);
    }
  }
}

// ---------------- workspace map (bytes) — total ~43 MB ----------------
#define WS_HT    (size_t)0          // bf16 HbT tiled [32][16][4096]   4 MB
#define WS_AALT  ((size_t)4 << 20)  // bf16 A[l][bh]                   4 MB
#define WS_WHT   ((size_t)8 << 20)  // bf16 WhT tiled [16][16][4096]   2 MB
#define WS_WIB   ((size_t)10 << 20) // bf16 Wi[m][l] row-major         2 MB
#define WS_XB    ((size_t)12 << 20) // bf16 x rows (b,t,f)[l]          1.5 MB
#define WS_WTR   ((size_t)14 << 20) // bf16 WT_r[l][k][h]              8 MB
#define WS_WTZ   ((size_t)22 << 20)
#define WS_WTN   ((size_t)30 << 20)
#define WS_ENCIN ((size_t)38 << 20) // f32 ENCIN[(b,t,f)][m]           3 MB
#define WS_OFC0  ((size_t)41 << 20) // bf16 OUTFC ping                 64 KB
#define WS_OFC1  (((size_t)41 << 20) + (64 << 10))
#define WS_BRZ   ((size_t)42 << 20) // f32 [1024][64]                  256 KB
#define WS_BZZ   (((size_t)42 << 20) + (256 << 10))
#define WS_BNH   (((size_t)42 << 20) + (512 << 10))
#define WS_BNI   (((size_t)42 << 20) + (768 << 10))

extern "C" void kernel_launch(void* const* d_in, const int* in_sizes, int n_in,
                              void* d_out, int out_size, void* d_ws, size_t ws_size,
                              hipStream_t stream) {
  const float* x   = (const float*)d_in[0];
  const float* Wi  = (const float*)d_in[1];
  const float* Wh  = (const float*)d_in[2];
  const float* Wrh = (const float*)d_in[3];
  const float* brh = (const float*)d_in[4];
  const float* Wri = (const float*)d_in[5];
  const float* bri = (const float*)d_in[6];
  const float* Wzh = (const float*)d_in[7];
  const float* bzh = (const float*)d_in[8];
  const float* Wzi = (const float*)d_in[9];
  const float* bzi = (const float*)d_in[10];
  const float* Wnh = (const float*)d_in[11];
  const float* bnh = (const float*)d_in[12];
  const float* Wni = (const float*)d_in[13];
  const float* bni = (const float*)d_in[14];
  const float* fcw = (const float*)d_in[15];
  const float* fcb = (const float*)d_in[16];
  float* out = (float*)d_out;

  char* ws = (char*)d_ws;
  u16*   HbT   = (u16*)(ws + WS_HT);
  u16*   Aalt  = (u16*)(ws + WS_AALT);
  u16*   WhT   = (u16*)(ws + WS_WHT);
  u16*   Wib   = (u16*)(ws + WS_WIB);
  u16*   xb    = (u16*)(ws + WS_XB);
  u16*   WTr   = (u16*)(ws + WS_WTR);
  u16*   WTz   = (u16*)(ws + WS_WTZ);
  u16*   WTn   = (u16*)(ws + WS_WTN);
  float* ENCIN = (float*)(ws + WS_ENCIN);
  u16*   OFC0  = (u16*)(ws + WS_OFC0);
  u16*   OFC1  = (u16*)(ws + WS_OFC1);
  float* BRZ   = (float*)(ws + WS_BRZ);
  float* BZZ   = (float*)(ws + WS_BZZ);
  float* BNH   = (float*)(ws + WS_BNH);
  float* BNI   = (float*)(ws + WS_BNI);

  k_prep<<<5376, 256, 0, stream>>>(Wh, Wi, x, WhT, Wib, xb, Wrh, Wzh, Wnh, WTr, WTz, WTn,
                                   brh, bri, bzh, bzi, bnh, bni, BRZ, BZZ, BNH, BNI);
  // all-timestep encoder input attn: ENCIN[(b,t,f)][m] = sum_l x * Wi[m,l]
  k_gemm_nt<<<dim3(8, 12), 256, 0, stream>>>(xb, Wib, ENCIN, 1024, 1024);

  // encoder: t=0 has H=0 -> skip hidden-attn GEMM, Z-path gates
  k_gates<1, 1, 0, 1><<<512, 512, 0, stream>>>(Aalt, WTr, WTz, WTn, BRZ, BZZ, BNH, BNI,
                                               Wri, Wzi, Wni, ENCIN, OFC0, Wib, fcw, fcb,
                                               out, OFC0, 0, 0, HbT);
  for (int t = 1; t < T_; ++t) {
    k_gemm_t<<<dim3(32, 16), 256, 0, stream>>>(WhT, HbT, Aalt);
    if (t < T_ - 1)
      k_gates<1, 0, 0, 1><<<512, 512, 0, stream>>>(Aalt, WTr, WTz, WTn, BRZ, BZZ, BNH, BNI,
                                                   Wri, Wzi, Wni, ENCIN, OFC0, Wib, fcw, fcb,
                                                   out, OFC0, t, 0, HbT);
    else
      k_gates<1, 0, 1, 1><<<512, 512, 0, stream>>>(Aalt, WTr, WTz, WTn, BRZ, BZZ, BNH, BNI,
                                                   Wri, Wzi, Wni, ENCIN, OFC0, Wib, fcw, fcb,
                                                   out, OFC0, t, 0, HbT);
  }
  // decoder: s = 0..10 (step 11's hidden update is unused)
  for (int s = 0; s <= 10; ++s) {
    const u16* ofr = (s & 1) ? OFC1 : OFC0;
    u16*       ofw = (s & 1) ? OFC0 : OFC1;
    k_gemm_t<<<dim3(32, 16), 256, 0, stream>>>(WhT, HbT, Aalt);
    if (s < 10)
      k_gates<0, 0, 1, 1><<<512, 512, 0, stream>>>(Aalt, WTr, WTz, WTn, BRZ, BZZ, BNH, BNI,
                                                   Wri, Wzi, Wni, ENCIN, ofr, Wib, fcw, fcb,
                                                   out, ofw, 0, s + 1, HbT);
    else
      k_gates<0, 0, 1, 0><<<512, 512, 0, stream>>>(Aalt, WTr, WTz, WTn, BRZ, BZZ, BNH, BNI,
                                                   Wri, Wzi, Wni, ENCIN, ofr, Wib, fcw, fcb,
                                                   out, ofw, 0, s + 1, HbT);
  }
}

// Round 19
// 673.276 us; speedup vs baseline: 5.0509x; 1.0231x over previous
//
#include <hip/hip_runtime.h>

#define T_ 12
#define L_ 1024
#define H_ 64
#define HOR_ 12
#define BH_ 2048

typedef unsigned short u16;
typedef __attribute__((ext_vector_type(8))) __bf16 bf16x8;
typedef __attribute__((ext_vector_type(8))) u16 u16x8;
typedef __attribute__((ext_vector_type(4))) float f32x4;

__device__ __forceinline__ u16 f2b(float f) {
  union { float f; unsigned u; } v; v.f = f;
  unsigned r = v.u + 0x7FFFu + ((v.u >> 16) & 1u);
  return (u16)(r >> 16);
}
__device__ __forceinline__ float b2f(u16 b) {
  union { unsigned u; float f; } v; v.u = ((unsigned)b) << 16;
  return v.f;
}
__device__ __forceinline__ void gld16(const void* g, void* l) {
  __builtin_amdgcn_global_load_lds((const __attribute__((address_space(1))) void*)g,
                                   (__attribute__((address_space(3))) void*)l, 16, 0, 0);
}

// 64x64 fragment-tile transform: (rw,cw) -> ci*8+e
//   ci = (((rw>>5)*2 + ((rw>>4)&1))*2 + (cw>>5))*64 + (rw&15) + ((cw>>3)&3)*16, e = cw&7

// ---- fused prep ----
__global__ __launch_bounds__(256) void k_prep(
    const float* __restrict__ Wh, const float* __restrict__ Wi, const float* __restrict__ x,
    u16* __restrict__ WhT, u16* __restrict__ Wib, u16* __restrict__ xb,
    const float* __restrict__ Wr, const float* __restrict__ Wz, const float* __restrict__ Wn,
    u16* __restrict__ WTr, u16* __restrict__ WTz, u16* __restrict__ WTn,
    const float* __restrict__ brh, const float* __restrict__ bri,
    const float* __restrict__ bzh, const float* __restrict__ bzi,
    const float* __restrict__ bnh, const float* __restrict__ bni,
    float* __restrict__ BRZ, float* __restrict__ BZZ,
    float* __restrict__ BNH, float* __restrict__ BNI) {
  __shared__ u16 lds[64][66];
  const int bid = blockIdx.x, tid = threadIdx.x;
  if (bid < 1792) {                       // ---- cvt: Wi | x ----
    const float* in; u16* out; int i;
    if (bid < 1024) { in = Wi; out = Wib; i = bid * 256 + tid; }
    else            { in = x;  out = xb;  i = (bid - 1024) * 256 + tid; }
    float4 v = ((const float4*)in)[i];
    ushort4 o;
    o.x = f2b(v.x); o.y = f2b(v.y); o.z = f2b(v.z); o.w = f2b(v.w);
    ((ushort4*)out)[i] = o;
  } else if (bid < 2048) {                // ---- WhT: tile Wh into fragment order ----
    const int q = bid - 1792;
    const int mt = q >> 4, kt = q & 15;
    u16* dst = WhT + (size_t)(mt * 16 + kt) * 4096;
#pragma unroll
    for (int j = 0; j < 2; ++j) {
      int ci = j * 256 + tid;
      int ln = ci & 63, kt2 = (ci >> 6) & 1, uu = (ci >> 7) & 1, gh = (ci >> 8) & 1;
      int rw = gh * 32 + uu * 16 + (ln & 15);
      int cw0 = kt2 * 32 + (ln >> 4) * 8;
      const float* src = Wh + (size_t)(mt * 64 + rw) * 1024 + kt * 64 + cw0;
      float4 v0 = *(const float4*)src, v1 = *(const float4*)(src + 4);
      u16x8 o;
      o[0] = f2b(v0.x); o[1] = f2b(v0.y); o[2] = f2b(v0.z); o[3] = f2b(v0.w);
      o[4] = f2b(v1.x); o[5] = f2b(v1.y); o[6] = f2b(v1.z); o[7] = f2b(v1.w);
      *(u16x8*)(dst + ci * 8) = o;
    }
  } else if (bid < 5120) {                // ---- transpose WT[l][k][h] = W[l][h][k] ----
    const int q = bid - 2048;
    const int sel = q >> 10, l = q & 1023;
    const float* w = (sel == 0 ? Wr : sel == 1 ? Wz : Wn) + (size_t)l * 4096;
    u16* t = (sel == 0 ? WTr : sel == 1 ? WTz : WTn) + (size_t)l * 4096;
#pragma unroll
    for (int j = 0; j < 16; ++j) {
      int idx = j * 256 + tid;
      lds[idx & 63][idx >> 6] = f2b(w[idx]);
    }
    __syncthreads();
#pragma unroll
    for (int j = 0; j < 2; ++j) {
      int w8 = j * 256 + tid;
      int k = w8 >> 3, h0 = (w8 & 7) * 8;
      u16x8 v;
#pragma unroll
      for (int e = 0; e < 8; ++e) v[e] = lds[k][h0 + e];
      *(u16x8*)(t + k * 64 + h0) = v;
    }
  } else {                                // ---- bias transpose+combine ----
    const int idx = (bid - 5120) * 256 + tid;
    const int l = idx >> 6, k = idx & 63;
    const int i = k * 1024 + l, o = l * 64 + k;
    BRZ[o] = brh[i] + bri[i];
    BZZ[o] = bzh[i] + bzi[i];
    BNH[o] = bnh[i];
    BNI[o] = bni[i];
  }
}

// -------- recurrent GEMM: 64x64 tile, tiled operands, single-buffered,
// -------- FOUR K-subtiles staged per barrier pair (8 barriers total)
__global__ __launch_bounds__(256, 2) void k_gemm_t(const u16* __restrict__ WhT,
                                                   const u16* __restrict__ HbT,
                                                   u16* __restrict__ C) {
  __shared__ __align__(16) u16 lA[16384];   // 4 subtiles x 8 KB
  __shared__ __align__(16) u16 lB[16384];
  const int tid = threadIdx.x;
  const int lane = tid & 63, wv = tid >> 6;
  const int mt = blockIdx.y, nt = blockIdx.x;
  const int gA = wv >> 1, gB = wv & 1;
  const int r16 = lane & 15, q4 = lane >> 4;
  const u16* srcA = WhT + (size_t)mt * 16 * 4096;
  const u16* srcB = HbT + (size_t)nt * 16 * 4096;
  f32x4 acc[2][2] = {};
  for (int s = 0; s < 16; s += 4) {
    __syncthreads();
#pragma unroll
    for (int j = 0; j < 8; ++j) {          // 2048 chunks each of A,B (8/thread)
      int ci = j * 256 + tid;
      gld16(srcA + (size_t)s * 4096 + ci * 8, lA + ci * 8);
      gld16(srcB + (size_t)s * 4096 + ci * 8, lB + ci * 8);
    }
    __syncthreads();
#pragma unroll
    for (int ss = 0; ss < 4; ++ss) {
#pragma unroll
      for (int kt = 0; kt < 2; ++kt) {
        bf16x8 af[2], bfv[2];
#pragma unroll
        for (int u = 0; u < 2; ++u) {
          af[u]  = *(const bf16x8*)&lA[ss * 4096 + ((gA * 2 + u) * 2 + kt) * 512 + lane * 8];
          bfv[u] = *(const bf16x8*)&lB[ss * 4096 + ((gB * 2 + u) * 2 + kt) * 512 + lane * 8];
        }
#pragma unroll
        for (int i = 0; i < 2; ++i)
#pragma unroll
          for (int j = 0; j < 2; ++j)
            acc[i][j] = __builtin_amdgcn_mfma_f32_16x16x32_bf16(af[i], bfv[j], acc[i][j], 0, 0, 0);
      }
    }
  }
#pragma unroll
  for (int i = 0; i < 2; ++i)
#pragma unroll
    for (int j = 0; j < 2; ++j)
#pragma unroll
      for (int e = 0; e < 4; ++e) {
        size_t row = mt * 64 + gA * 32 + i * 16 + q4 * 4 + e;
        size_t col = nt * 64 + gB * 32 + j * 16 + r16;
        C[row * BH_ + col] = f2b(acc[i][j][e]);
      }
}

// -------- legacy 64x128 NT GEMM (one-time ENCIN), row-major operands --------
__global__ __launch_bounds__(256) void k_gemm_nt(const u16* __restrict__ A,
                                                 const u16* __restrict__ Bm,
                                                 float* __restrict__ C, int N, int K) {
  __shared__ __align__(16) u16 lA[64 * 64];
  __shared__ __align__(16) u16 lB[128 * 64];
  const int tid = threadIdx.x;
  const int lane = tid & 63, wv = tid >> 6;
  const int m0 = blockIdx.y * 64, n0 = blockIdx.x * 128;
  const int g2 = wv >> 1, gb = wv & 1;
  const int wm = g2 * 32, wn = gb * 64;
  const int r16 = lane & 15, q4 = lane >> 4;
  f32x4 acc[2][4] = {};
  for (int k0 = 0; k0 < K; k0 += 64) {
    __syncthreads();
#pragma unroll
    for (int j = 0; j < 2; ++j) {
      int ci = j * 256 + tid;
      int ln = ci & 63, kt = (ci >> 6) & 1, u = (ci >> 7) & 1, g = ci >> 8;
      int row = g * 32 + u * 16 + (ln & 15), c = kt * 4 + ((ln >> 4) & 3);
      gld16(A + (size_t)(m0 + row) * K + k0 + c * 8, lA + ci * 8);
    }
#pragma unroll
    for (int j = 0; j < 4; ++j) {
      int ci = j * 256 + tid;
      int ln = ci & 63, kt = (ci >> 6) & 1, u = (ci >> 7) & 3, g = ci >> 9;
      int row = g * 64 + u * 16 + (ln & 15), c = kt * 4 + ((ln >> 4) & 3);
      gld16(Bm + (size_t)(n0 + row) * K + k0 + c * 8, lB + ci * 8);
    }
    __syncthreads();
#pragma unroll
    for (int kt = 0; kt < 2; ++kt) {
      bf16x8 af[2], bfv[4];
#pragma unroll
      for (int u = 0; u < 2; ++u)
        af[u] = *(const bf16x8*)&lA[((g2 * 2 + u) * 2 + kt) * 512 + lane * 8];
#pragma unroll
      for (int u = 0; u < 4; ++u)
        bfv[u] = *(const bf16x8*)&lB[((gb * 4 + u) * 2 + kt) * 512 + lane * 8];
#pragma unroll
      for (int i = 0; i < 2; ++i)
#pragma unroll
        for (int j = 0; j < 4; ++j)
          acc[i][j] = __builtin_amdgcn_mfma_f32_16x16x32_bf16(af[i], bfv[j], acc[i][j], 0, 0, 0);
    }
  }
#pragma unroll
  for (int i = 0; i < 2; ++i)
#pragma unroll
    for (int j = 0; j < 4; ++j)
#pragma unroll
      for (int e = 0; e < 4; ++e) {
        size_t row = m0 + wm + i * 16 + q4 * 4 + e;
        size_t col = n0 + wn + j * 16 + r16;
        C[row * N + col] = acc[i][j][e];
      }
}

// -------- gates (+fused decoder-input-attn prologue, +fused fc epilogue) --------
template <int ENC, int Z, int FC, int WH>
__global__ __launch_bounds__(512, 4) void k_gates(
    const u16* __restrict__ Aalt, const u16* __restrict__ WTr, const u16* __restrict__ WTz,
    const u16* __restrict__ WTn, const float* __restrict__ BRZ, const float* __restrict__ BZZ,
    const float* __restrict__ BNH, const float* __restrict__ BNI,
    const float* __restrict__ Wir, const float* __restrict__ Wiz, const float* __restrict__ Win,
    const float* __restrict__ inp, const u16* __restrict__ OUTFC_r, const u16* __restrict__ Wib,
    const float* __restrict__ fcw, const float* __restrict__ fcb,
    float* __restrict__ outp, u16* __restrict__ OUTFC_w, int t, int s_out,
    u16* __restrict__ HbT) {
  __shared__ __align__(8) u16 lout[BH_ * 2];
  __shared__ __align__(16) u16 lWi[2048];
  __shared__ float din[2][2][32];       // [li][f][b]
  const int tid = threadIdx.x;
  const int lane = tid & 63, wv = tid >> 6;
  const int li = wv >> 2, mh = (wv >> 1) & 1, nh = wv & 1;
  const int bid = blockIdx.x;
  const int wg = (bid & 7) * 64 + (bid >> 3);   // chunked XCD map
  const int l = wg * 2 + li;
  const int r16 = lane & 15, q4 = lane >> 4;

  if (ENC) {
    if (tid < 128) {
      int b = tid & 31, f = (tid >> 5) & 1, li2 = tid >> 6;
      din[li2][f][b] = inp[(((size_t)b * T_ + t) * 2 + f) * L_ + wg * 2 + li2];
    }
    __syncthreads();
  } else {
    if (tid < 256) ((uint4*)lWi)[tid] = ((const uint4*)(Wib + (size_t)(wg * 2) * 1024))[tid];
    __syncthreads();
    const int pair = tid >> 3, sub = tid & 7;
    const int pb = pair >> 1, pl = pair & 1;
    const u16* orow = OUTFC_r + pb * 1024 + sub * 128;
    const u16* wrow = lWi + pl * 1024 + sub * 128;
    float s = 0.f;
#pragma unroll
    for (int j = 0; j < 16; ++j) {
      u16x8 o = *(const u16x8*)(orow + j * 8);
      u16x8 w = *(const u16x8*)(wrow + j * 8);
#pragma unroll
      for (int e = 0; e < 8; ++e) s += b2f(o[e]) * b2f(w[e]);
    }
    s += __shfl_xor(s, 1); s += __shfl_xor(s, 2); s += __shfl_xor(s, 4);
    if (sub == 0) { din[pl][0][pb] = s; din[pl][1][pb] = 0.f; }
    __syncthreads();
  }

  const u16* al = Aalt + (size_t)l * BH_;
  bf16x8 a[2];
  f32x4 aR[2] = {}, aZ[2] = {}, aN[2] = {};
  if (Z == 0) {
#pragma unroll
    for (int kt = 0; kt < 2; ++kt)
      a[kt] = *(const bf16x8*)&al[(mh * 16 + r16) * 64 + kt * 32 + q4 * 8];
    const size_t wbase = (size_t)l * 4096 + (size_t)(nh * 32 + r16) * 64 + q4 * 8;
#define DO_GATE(W, acc)                                                              \
    {                                                                                \
      bf16x8 w00 = *(const bf16x8*)&W[wbase];                                        \
      bf16x8 w01 = *(const bf16x8*)&W[wbase + 32];                                   \
      bf16x8 w10 = *(const bf16x8*)&W[wbase + 1024];                                 \
      bf16x8 w11 = *(const bf16x8*)&W[wbase + 1024 + 32];                            \
      acc[0] = __builtin_amdgcn_mfma_f32_16x16x32_bf16(a[0], w00, acc[0], 0, 0, 0);  \
      acc[0] = __builtin_amdgcn_mfma_f32_16x16x32_bf16(a[1], w01, acc[0], 0, 0, 0);  \
      acc[1] = __builtin_amdgcn_mfma_f32_16x16x32_bf16(a[0], w10, acc[1], 0, 0, 0);  \
      acc[1] = __builtin_amdgcn_mfma_f32_16x16x32_bf16(a[1], w11, acc[1], 0, 0, 0);  \
    }
    DO_GATE(WTr, aR)
    DO_GATE(WTz, aZ)
    DO_GATE(WTn, aN)
#undef DO_GATE
  }

  float i0v[4], i1v[4];
#pragma unroll
  for (int e = 0; e < 4; ++e) {
    const int bb = mh * 16 + q4 * 4 + e;
    i0v[e] = din[li][0][bb];
    i1v[e] = ENC ? din[li][1][bb] : 0.f;
  }
#pragma unroll
  for (int ntl = 0; ntl < 2; ++ntl) {
    const int kk = nh * 32 + ntl * 16 + r16;
    const float vbr  = BRZ[l * 64 + kk];
    const float vbz  = BZZ[l * 64 + kk];
    const float vbnh = BNH[l * 64 + kk];
    const float vbni = BNI[l * 64 + kk];
    const float wr0 = Wir[l * 128 + kk], wr1 = Wir[l * 128 + 64 + kk];
    const float wz0 = Wiz[l * 128 + kk], wz1 = Wiz[l * 128 + 64 + kk];
    const float wn0 = Win[l * 128 + kk], wn1 = Win[l * 128 + 64 + kk];
#pragma unroll
    for (int e = 0; e < 4; ++e) {
      const int bb = mh * 16 + q4 * 4 + e;
      const float i0 = i0v[e], i1 = i1v[e];
      const float gr = aR[ntl][e] + vbr + i0 * wr0 + i1 * wr1;
      const float gz = aZ[ntl][e] + vbz + i0 * wz0 + i1 * wz1;
      const float gnh = aN[ntl][e] + vbnh;
      const float gni = i0 * wn0 + i1 * wn1 + vbni;
      const float rr = 1.f / (1.f + __expf(-gr));
      const float zz = 1.f / (1.f + __expf(-gz));
      const float xx = rr * gnh + gni;
      const float ex = __expf(2.f * xx);
      const float nn = (ex - 1.f) / (ex + 1.f);
      const float av = Z ? 0.f : b2f(al[bb * 64 + kk]);
      lout[(bb * 64 + kk) * 2 + li] = f2b((1.f - zz) * nn + zz * av);
    }
  }
  __syncthreads();

  if (WH) {   // ---- HbT write: tiled fragment layout ----
    const int c0 = wg * 2;
    const int ktile = c0 >> 6;
    const int cw = c0 & 63;
    const int kt2 = cw >> 5, q = (cw >> 3) & 3, e = cw & 7;
    for (int i = tid; i < BH_; i += 512) {
      int rw = i & 63, nt = i >> 6;
      int ci = (((rw >> 5) * 2 + ((rw >> 4) & 1)) * 2 + kt2) * 64 + (rw & 15) + q * 16;
      *(unsigned*)(HbT + (size_t)(nt * 16 + ktile) * 4096 + ci * 8 + e) =
          *(const unsigned*)&lout[i * 2];
    }
  }

  if (FC) {
    if (tid < 64) {
      const int b = tid & 31, li2 = tid >> 5;
      const int lf = wg * 2 + li2;
      float acc = 0.f;
      const float* wp = fcw + (size_t)lf * 64;
#pragma unroll 8
      for (int hh = 0; hh < 64; ++hh) {
        int h = (hh + b) & 63;
        acc += b2f(lout[(b * 64 + h) * 2 + li2]) * wp[h];
      }
      acc += fcb[lf];
      outp[((size_t)b * HOR_ + s_out) * L_ + lf] = acc;
      OUTFC_w[(size_t)b * 1024 + lf] = f2b(acc);
    }
  }
}

// ---------------- workspace map (bytes) — total ~43 MB ----------------
#define WS_HT    (size_t)0          // bf16 HbT tiled [32][16][4096]   4 MB
#define WS_AALT  ((size_t)4 << 20)  // bf16 A[l][bh]                   4 MB
#define WS_WHT   ((size_t)8 << 20)  // bf16 WhT tiled [16][16][4096]   2 MB
#define WS_WIB   ((size_t)10 << 20) // bf16 Wi[m][l] row-major         2 MB
#define WS_XB    ((size_t)12 << 20) // bf16 x rows (b,t,f)[l]          1.5 MB
#define WS_WTR   ((size_t)14 << 20) // bf16 WT_r[l][k][h]              8 MB
#define WS_WTZ   ((size_t)22 << 20)
#define WS_WTN   ((size_t)30 << 20)
#define WS_ENCIN ((size_t)38 << 20) // f32 ENCIN[(b,t,f)][m]           3 MB
#define WS_OFC0  ((size_t)41 << 20) // bf16 OUTFC ping                 64 KB
#define WS_OFC1  (((size_t)41 << 20) + (64 << 10))
#define WS_BRZ   ((size_t)42 << 20) // f32 [1024][64]                  256 KB
#define WS_BZZ   (((size_t)42 << 20) + (256 << 10))
#define WS_BNH   (((size_t)42 << 20) + (512 << 10))
#define WS_BNI   (((size_t)42 << 20) + (768 << 10))

extern "C" void kernel_launch(void* const* d_in, const int* in_sizes, int n_in,
                              void* d_out, int out_size, void* d_ws, size_t ws_size,
                              hipStream_t stream) {
  const float* x   = (const float*)d_in[0];
  const float* Wi  = (const float*)d_in[1];
  const float* Wh  = (const float*)d_in[2];
  const float* Wrh = (const float*)d_in[3];
  const float* brh = (const float*)d_in[4];
  const float* Wri = (const float*)d_in[5];
  const float* bri = (const float*)d_in[6];
  const float* Wzh = (const float*)d_in[7];
  const float* bzh = (const float*)d_in[8];
  const float* Wzi = (const float*)d_in[9];
  const float* bzi = (const float*)d_in[10];
  const float* Wnh = (const float*)d_in[11];
  const float* bnh = (const float*)d_in[12];
  const float* Wni = (const float*)d_in[13];
  const float* bni = (const float*)d_in[14];
  const float* fcw = (const float*)d_in[15];
  const float* fcb = (const float*)d_in[16];
  float* out = (float*)d_out;

  char* ws = (char*)d_ws;
  u16*   HbT   = (u16*)(ws + WS_HT);
  u16*   Aalt  = (u16*)(ws + WS_AALT);
  u16*   WhT   = (u16*)(ws + WS_WHT);
  u16*   Wib   = (u16*)(ws + WS_WIB);
  u16*   xb    = (u16*)(ws + WS_XB);
  u16*   WTr   = (u16*)(ws + WS_WTR);
  u16*   WTz   = (u16*)(ws + WS_WTZ);
  u16*   WTn   = (u16*)(ws + WS_WTN);
  float* ENCIN = (float*)(ws + WS_ENCIN);
  u16*   OFC0  = (u16*)(ws + WS_OFC0);
  u16*   OFC1  = (u16*)(ws + WS_OFC1);
  float* BRZ   = (float*)(ws + WS_BRZ);
  float* BZZ   = (float*)(ws + WS_BZZ);
  float* BNH   = (float*)(ws + WS_BNH);
  float* BNI   = (float*)(ws + WS_BNI);

  k_prep<<<5376, 256, 0, stream>>>(Wh, Wi, x, WhT, Wib, xb, Wrh, Wzh, Wnh, WTr, WTz, WTn,
                                   brh, bri, bzh, bzi, bnh, bni, BRZ, BZZ, BNH, BNI);
  // all-timestep encoder input attn: ENCIN[(b,t,f)][m] = sum_l x * Wi[m,l]
  k_gemm_nt<<<dim3(8, 12), 256, 0, stream>>>(xb, Wib, ENCIN, 1024, 1024);

  // encoder: t=0 has H=0 -> skip hidden-attn GEMM, Z-path gates
  k_gates<1, 1, 0, 1><<<512, 512, 0, stream>>>(Aalt, WTr, WTz, WTn, BRZ, BZZ, BNH, BNI,
                                               Wri, Wzi, Wni, ENCIN, OFC0, Wib, fcw, fcb,
                                               out, OFC0, 0, 0, HbT);
  for (int t = 1; t < T_; ++t) {
    k_gemm_t<<<dim3(32, 16), 256, 0, stream>>>(WhT, HbT, Aalt);
    if (t < T_ - 1)
      k_gates<1, 0, 0, 1><<<512, 512, 0, stream>>>(Aalt, WTr, WTz, WTn, BRZ, BZZ, BNH, BNI,
                                                   Wri, Wzi, Wni, ENCIN, OFC0, Wib, fcw, fcb,
                                                   out, OFC0, t, 0, HbT);
    else
      k_gates<1, 0, 1, 1><<<512, 512, 0, stream>>>(Aalt, WTr, WTz, WTn, BRZ, BZZ, BNH, BNI,
                                                   Wri, Wzi, Wni, ENCIN, OFC0, Wib, fcw, fcb,
                                                   out, OFC0, t, 0, HbT);
  }
  // decoder: s = 0..10 (step 11's hidden update is unused)
  for (int s = 0; s <= 10; ++s) {
    const u16* ofr = (s & 1) ? OFC1 : OFC0;
    u16*       ofw = (s & 1) ? OFC0 : OFC1;
    k_gemm_t<<<dim3(32, 16), 256, 0, stream>>>(WhT, HbT, Aalt);
    if (s < 10)
      k_gates<0, 0, 1, 1><<<512, 512, 0, stream>>>(Aalt, WTr, WTz, WTn, BRZ, BZZ, BNH, BNI,
                                                   Wri, Wzi, Wni, ENCIN, ofr, Wib, fcw, fcb,
                                                   out, ofw, 0, s + 1, HbT);
    else
      k_gates<0, 0, 1, 0><<<512, 512, 0, stream>>>(Aalt, WTr, WTz, WTn, BRZ, BZZ, BNH, BNI,
                                                   Wri, Wzi, Wni, ENCIN, ofr, Wib, fcw, fcb,
                                                   out, ofw, 0, s + 1, HbT);
  }
}